// Round 7
// baseline (43012.527 us; speedup 1.0000x reference)
//
#include <hip/hip_runtime.h>
#include <hip/hip_bf16.h>

// Problem constants (B=256, T=512, H=512, IN=1, future=64)
#define TT  512
#define BB  256
#define HH  512
#define FUT 64

// Output is FP32 (r6 diagnosis: harness reads d_out as float32; the constant
// absmax 0.1298828 across rounds was max|ref| over the zero half of a
// half-written buffer). Beacons (on failure) are float 2^(20+code)*(1+m/128):
//  0: n_in!=22  1: in_sizes mismatch @m  2: ws too small  3: exec count wrong
//  4: obuf NaN  6: out_size wrong

struct Hdr {
  int   dtflag;              // 0 = bf16 inputs, 1 = fp32 inputs (expect 1)
  int   count;               // kernel-completion counter (expect 1214)
  float pad[14];
  float obuf[256];           // decode feedback o[b] (fp32, exact)
};
#define STATE_OFF 8192
#define FSZ ((size_t)BB * HH * sizeof(float))         // 512 KB
#define NEED_WS (STATE_OFF + 6 * FSZ)

__device__ __forceinline__ float bf2f(short s) {
  unsigned u = ((unsigned)(unsigned short)s) << 16;
  return __builtin_bit_cast(float, u);
}
__device__ __forceinline__ float ldf(const void* p, long i, int dt) {
  return dt ? ((const float*)p)[i] : bf2f(((const short*)p)[i]);
}

__global__ void beacon_kernel(float* dout, float v) {
  if (threadIdx.x == 0) dout[0] = v;
}

// dtype probe: fp32 data read as bf16 shows |v|>>1e3 / NaN junk.
__global__ __launch_bounds__(256) void probe1_kernel(const void* w, Hdr* hdr) {
  const int tid = threadIdx.x;
  const short* s = (const short*)w;
  float mx = 0.f;
  #pragma unroll
  for (int i = 0; i < 16; ++i) {
    float v = fabsf(bf2f(s[tid * 16 + i]));
    if (!(v == v)) v = 1e30f;
    mx = fmaxf(mx, v);
  }
  #pragma unroll
  for (int off = 32; off > 0; off >>= 1) mx = fmaxf(mx, __shfl_down(mx, off));
  __shared__ float wmax[4];
  if ((tid & 63) == 0) wmax[tid >> 6] = mx;
  __syncthreads();
  if (tid == 0) {
    float m = fmaxf(fmaxf(wmax[0], wmax[1]), fmaxf(wmax[2], wmax[3]));
    hdr->dtflag = (m > 1000.f) ? 1 : 0;
  }
}

// Pure-fp32 LSTM timestep. gates = A1@W1^T (+A2@W2^T) (+ sv*wih_col) + bih+bhh.
// Grid 512 x 256thr: 16 batch-tiles x 32 unit-slices; wave = gate (i,f,g,o).
// Cross-validated vs independent scalar miniref (r6): semantics correct.
__global__ __launch_bounds__(256) void lstm_step_f32(
    const float* __restrict__ A1, const float* __restrict__ A2, int nseg,
    const void* __restrict__ W1, const void* __restrict__ W2,
    const void* __restrict__ bih, const void* __restrict__ bhh,
    int in_mode,                     // 0: x[b,t], 1: none, 2: hdr->obuf[b]
    const void* __restrict__ x, int t,
    const void* __restrict__ wih_col,
    float* __restrict__ C, float* __restrict__ Hout,
    Hdr* __restrict__ hdr)
{
  const int dt   = hdr->dtflag;
  const int tid  = threadIdx.x;
  const int lane = tid & 63;
  const int wv   = tid >> 6;
  const int mt   = blockIdx.x >> 5;
  const int ks   = blockIdx.x & 31;
  const int u    = lane & 15;
  const int bq   = lane >> 4;

  __shared__ float4 Hs4[16][33];
  __shared__ float4 Ws4[4][16][33];
  __shared__ float  gLDS[4][16][17];

  float acc[4] = {0.f, 0.f, 0.f, 0.f};

  for (int seg = 0; seg < nseg; ++seg) {
    const float* A = seg ? A2 : A1;
    const void*  W = seg ? W2 : W1;
    for (int ch = 0; ch < 4; ++ch) {
      __syncthreads();
      for (int it = tid; it < 512; it += 256) {
        const int row = it >> 5, kv = it & 31;
        Hs4[row][kv] = ((const float4*)A)[(mt*16 + row)*128 + ch*32 + kv];
      }
      for (int it = tid; it < 2048; it += 256) {
        const int g = it >> 9, row = (it >> 5) & 15, kv = it & 31;
        const long wrow = (long)(g*512 + ks*16 + row);
        if (dt) {
          Ws4[g][row][kv] = ((const float4*)W)[wrow*128 + ch*32 + kv];
        } else {
          const short* wp = (const short*)W + wrow*512 + ch*128 + kv*4;
          Ws4[g][row][kv] = make_float4(bf2f(wp[0]), bf2f(wp[1]),
                                        bf2f(wp[2]), bf2f(wp[3]));
        }
      }
      __syncthreads();
      #pragma unroll 8
      for (int kk = 0; kk < 32; ++kk) {
        const float4 w4 = Ws4[wv][u][kk];
        #pragma unroll
        for (int r = 0; r < 4; ++r) {
          const float4 h4 = Hs4[bq*4 + r][kk];
          acc[r] += h4.x*w4.x + h4.y*w4.y + h4.z*w4.z + h4.w*w4.w;
        }
      }
    }
  }

  #pragma unroll
  for (int r = 0; r < 4; ++r) gLDS[wv][bq*4 + r][u] = acc[r];
  __syncthreads();

  const int bl = tid >> 4;
  const int kk = tid & 15;
  const int bg = mt*16 + bl;
  const int kg = ks*16 + kk;

  float sv = 0.f;
  if (in_mode == 0)      sv = ldf(x, (long)bg*TT + t, dt);
  else if (in_mode == 2) sv = hdr->obuf[bg];

  float gv[4];
  #pragma unroll
  for (int g = 0; g < 4; ++g) {
    const int j = g*512 + kg;
    float v = gLDS[g][bl][kk] + ldf(bih, j, dt) + ldf(bhh, j, dt);
    if (in_mode != 1) v += sv * ldf(wih_col, j, dt);
    gv[g] = v;
  }
  const float ig = 1.f / (1.f + expf(-gv[0]));
  const float fg = 1.f / (1.f + expf(-gv[1]));
  const float gg = tanhf(gv[2]);
  const float og = 1.f / (1.f + expf(-gv[3]));
  const float cn = fg * C[bg*512 + kg] + ig * gg;
  C[bg*512 + kg]    = cn;
  Hout[bg*512 + kg] = og * tanhf(cn);

  if (blockIdx.x == 0 && tid == 0) atomicAdd(&hdr->count, 1);
}

// o[b] = h[b,:].w + bias -> fp32 obuf (decode feedback) and FP32 d_out col s
__global__ __launch_bounds__(64) void head_kernel(
    const float* __restrict__ Hin, const void* __restrict__ w,
    const void* __restrict__ bias, float* __restrict__ dout, int s,
    Hdr* __restrict__ hdr)
{
  const int dt = hdr->dtflag;
  const int b = blockIdx.x;
  const int lane = threadIdx.x;
  const float* hr = Hin + b*512 + lane*8;
  float sum = 0.f;
  #pragma unroll
  for (int j = 0; j < 8; ++j) sum += hr[j] * ldf(w, lane*8 + j, dt);
  #pragma unroll
  for (int off = 32; off > 0; off >>= 1) sum += __shfl_down(sum, off);
  if (lane == 0) {
    float o = sum + ldf(bias, 0, dt);
    hdr->obuf[b] = o;
    dout[b*FUT + s] = o;               // [B, future] fp32
    if (b == 0) atomicAdd(&hdr->count, 1);
  }
}

__global__ __launch_bounds__(64) void verdict_kernel(
    Hdr* __restrict__ hdr, float* __restrict__ dout)
{
  if (threadIdx.x == 0) {
    int code = -1, m = 0;
    const int cnt = hdr->count;
    const float o0 = hdr->obuf[0];
    if (cnt != 1214)      { code = 3; m = (cnt >> 4) & 127; }
    else if (!(o0 == o0)) { code = 4; m = 0; }
    if (code >= 0) dout[0] = ldexpf(1.f + (float)m / 128.f, 20 + code);
  }
}

extern "C" void kernel_launch(void* const* d_in, const int* in_sizes, int n_in,
                              void* d_out, int out_size, void* d_ws, size_t ws_size,
                              hipStream_t stream) {
  float* dout = (float*)d_out;

  static const int exp_sizes[22] = {
    131072, 1, 2048, 1048576, 2048, 2048, 1048576, 1048576, 2048, 2048,
    512, 1, 2048, 1048576, 2048, 2048, 1048576, 1048576, 2048, 2048, 512, 1};
  int code = -1, m = 0;
  if (n_in != 22) { code = 0; m = n_in & 127; }
  else {
    for (int i = 0; i < 22; ++i)
      if (in_sizes[i] != exp_sizes[i]) { code = 1; m = i; break; }
  }
  if (code < 0 && out_size != BB * FUT) { code = 6; m = (out_size >> 8) & 127; }
  if (code < 0 && (d_ws == nullptr || ws_size < NEED_WS)) {
    code = 2; m = (int)(ws_size >> 16); if (m > 127) m = 127;
  }
  if (code >= 0) {
    float v = ldexpf(1.f + (float)m / 128.f, 20 + code);
    beacon_kernel<<<dim3(1), dim3(64), 0, stream>>>(dout, v);
    return;
  }

  const void* x      = d_in[0];
  const void* w_ih0  = d_in[2];
  const void* w_hh0  = d_in[3];
  const void* b_ih0  = d_in[4];
  const void* b_hh0  = d_in[5];
  const void* w_ih1  = d_in[6];
  const void* w_hh1  = d_in[7];
  const void* b_ih1  = d_in[8];
  const void* b_hh1  = d_in[9];
  const void* fc_w   = d_in[10];
  const void* fc_b   = d_in[11];
  const void* pw_ih0 = d_in[12];
  const void* pw_hh0 = d_in[13];
  const void* pb_ih0 = d_in[14];
  const void* pb_hh0 = d_in[15];
  const void* pw_ih1 = d_in[16];
  const void* pw_hh1 = d_in[17];
  const void* pb_ih1 = d_in[18];
  const void* pb_hh1 = d_in[19];
  const void* pfc_w  = d_in[20];
  const void* pfc_b  = d_in[21];

  char* ws = (char*)d_ws;
  Hdr* hdr = (Hdr*)ws;
  char* base = ws + STATE_OFF;
  float* C0 = (float*)(base);
  float* C1 = (float*)(base + FSZ);
  float* Ha[4];
  Ha[0] = (float*)(base + 2*FSZ);   // H0 ping
  Ha[1] = (float*)(base + 3*FSZ);   // H0 pong
  Ha[2] = (float*)(base + 4*FSZ);   // H1 ping
  Ha[3] = (float*)(base + 5*FSZ);   // H1 pong

  hipMemsetAsync(hdr, 0, STATE_OFF, stream);
  hipMemsetAsync(C0, 0, FSZ, stream);
  hipMemsetAsync(C1, 0, FSZ, stream);
  hipMemsetAsync(Ha[0], 0, FSZ, stream);
  hipMemsetAsync(Ha[2], 0, FSZ, stream);
  probe1_kernel<<<dim3(1), dim3(256), 0, stream>>>(w_hh0, hdr);

  dim3 grid(512), blk(256);
  for (int t = 0; t < TT; ++t) {
    const int cur = t & 1, nxt = cur ^ 1;
    lstm_step_f32<<<grid, blk, 0, stream>>>(Ha[cur], nullptr, 1, w_hh0, nullptr,
        b_ih0, b_hh0, 0, x, t, w_ih0, C0, Ha[nxt], hdr);
    lstm_step_f32<<<grid, blk, 0, stream>>>(Ha[nxt], Ha[2+cur], 2, w_ih1, w_hh1,
        b_ih1, b_hh1, 1, nullptr, 0, nullptr, C1, Ha[2+nxt], hdr);
  }
  head_kernel<<<dim3(BB), dim3(64), 0, stream>>>(Ha[2], fc_w, fc_b, dout, 0, hdr);

  for (int s = 1; s < FUT; ++s) {
    const int cur = (s - 1) & 1, nxt = cur ^ 1;
    lstm_step_f32<<<grid, blk, 0, stream>>>(Ha[cur], nullptr, 1, pw_hh0, nullptr,
        pb_ih0, pb_hh0, 2, nullptr, 0, pw_ih0, C0, Ha[nxt], hdr);
    lstm_step_f32<<<grid, blk, 0, stream>>>(Ha[nxt], Ha[2+cur], 2, pw_ih1, pw_hh1,
        pb_ih1, pb_hh1, 1, nullptr, 0, nullptr, C1, Ha[2+nxt], hdr);
    head_kernel<<<dim3(BB), dim3(64), 0, stream>>>(Ha[2+nxt], pfc_w, pfc_b, dout, s, hdr);
  }
  verdict_kernel<<<dim3(1), dim3(64), 0, stream>>>(hdr, dout);
}

// Round 8
// 22664.633 us; speedup vs baseline: 1.8978x; 1.8978x over previous
//
#include <hip/hip_runtime.h>
#include <hip/hip_bf16.h>

// Problem constants (B=256, T=512, H=512, IN=1, future=64)
#define TT  512
#define BB  256
#define HH  512
#define FUT 64

// Output dtype: FP32 (r6/r7 verified). Beacons: float 2^(20+code)*(1+m/128):
//  0: n_in!=22  1: in_sizes mismatch @m  2: ws too small (m = ws_size in MB)
//  3: exec count wrong  4: obuf NaN  6: out_size wrong

struct Hdr {
  int   dtflag;              // 0 = bf16 inputs, 1 = fp32 inputs (expect 1)
  int   count;               // step/head completion counter (expect 1214)
  float pad[14];
  float obuf[256];           // decode feedback o[b] (fp32, exact)
};

typedef __attribute__((ext_vector_type(8))) short short8;   // 8 x bf16
typedef __attribute__((ext_vector_type(4))) float floatx4;  // MFMA acc

// ---- ws layout (bytes) ----
#define OFF_BS0   (8192)
#define OFF_BS1   (16384)
#define OFF_PBS0  (24576)
#define OFF_PBS1  (32768)
#define OFF_C0    (40960)
#define OFF_C1    (OFF_C0 + 524288)
#define OFF_H0A   (OFF_C1 + 524288)
#define OFF_H0B   (OFF_H0A + 262144)
#define OFF_H1A   (OFF_H0B + 262144)
#define OFF_H1B   (OFF_H1A + 262144)
#define OFF_W     (OFF_H1B + 262144)
#define WSZ       (2097152)                     // one bf16 [2048,512] matrix
#define NEED_WS   ((size_t)OFF_W + 6 * WSZ)     // ~14.1 MB

__device__ __forceinline__ float bf2f(short s) {
  unsigned u = ((unsigned)(unsigned short)s) << 16;
  return __builtin_bit_cast(float, u);
}
__device__ __forceinline__ short f2bf(float f) {
  unsigned u = __builtin_bit_cast(unsigned, f);
  u = u + 0x7FFFu + ((u >> 16) & 1u);   // RNE
  return (short)(u >> 16);
}
__device__ __forceinline__ float ldf(const void* p, long i, int dt) {
  return dt ? ((const float*)p)[i] : bf2f(((const short*)p)[i]);
}

__global__ void beacon_kernel(float* dout, float v) {
  if (threadIdx.x == 0) dout[0] = v;
}

// dtype probe: fp32 data read as bf16 shows |v|>>1e3 / NaN junk.
__global__ __launch_bounds__(256) void probe1_kernel(const void* w, Hdr* hdr) {
  const int tid = threadIdx.x;
  const short* s = (const short*)w;
  float mx = 0.f;
  #pragma unroll
  for (int i = 0; i < 16; ++i) {
    float v = fabsf(bf2f(s[tid * 16 + i]));
    if (!(v == v)) v = 1e30f;
    mx = fmaxf(mx, v);
  }
  #pragma unroll
  for (int off = 32; off > 0; off >>= 1) mx = fmaxf(mx, __shfl_down(mx, off));
  __shared__ float wmax[4];
  if ((tid & 63) == 0) wmax[tid >> 6] = mx;
  __syncthreads();
  if (tid == 0) {
    float m = fmaxf(fmaxf(wmax[0], wmax[1]), fmaxf(wmax[2], wmax[3]));
    hdr->dtflag = (m > 1000.f) ? 1 : 0;
  }
}

// one-time: convert a [2048,512] input matrix to bf16 (4 elems/thread)
__global__ __launch_bounds__(256) void cvt_kernel(const void* src, short* dst,
                                                  const Hdr* hdr) {
  const int dt = hdr->dtflag;
  const long i = ((long)blockIdx.x * 256 + threadIdx.x) * 4;
  if (dt) {
    const float4 v = ((const float4*)src)[i >> 2];
    short4 o;
    o.x = f2bf(v.x); o.y = f2bf(v.y); o.z = f2bf(v.z); o.w = f2bf(v.w);
    ((short4*)dst)[i >> 2] = o;
  } else {
    ((short4*)dst)[i >> 2] = ((const short4*)src)[i >> 2];
  }
}

// one-time: bsum[j] = bih[j] + bhh[j], j in [0,2048)
__global__ __launch_bounds__(256) void bias_kernel(const void* bih,
                                                   const void* bhh,
                                                   float* bsum, const Hdr* hdr) {
  const int dt = hdr->dtflag;
  const int j = blockIdx.x * 256 + threadIdx.x;
  bsum[j] = ldf(bih, j, dt) + ldf(bhh, j, dt);
}

// bf16-MFMA LSTM timestep. gates = A1@W1^T (+A2@W2^T) (+ sv*wih_col) + bsum.
// Grid 128 blocks (4 batch-tiles x 32 unit-slices) x 256 thr; wave = gate
// (torch i,f,g,o). W bf16 [2048,512] row-major (B^T form, K contiguous).
// A bf16 [256,512]. C fp32. Fragment layouts per m89/m91:
//   A: row m=lane&15, k=quad*8+j ; B: col n=lane&15, k=quad*8+j
//   D: col=lane&15 (unit), row=quad*4+r (batch)
__global__ __launch_bounds__(256) void lstm_step_mfma(
    const short* __restrict__ A1, const short* __restrict__ A2, int nseg,
    const short* __restrict__ W1, const short* __restrict__ W2,
    const float* __restrict__ bsum,
    int in_mode,                     // 0: x[b,t], 1: none, 2: hdr->obuf[b]
    const void* __restrict__ x, int t,
    const void* __restrict__ wih_col,   // [2048] raw input array (dtype dt)
    float* __restrict__ C, short* __restrict__ Hout,
    Hdr* __restrict__ hdr)
{
  const int dt   = hdr->dtflag;
  const int tid  = threadIdx.x;
  const int lane = tid & 63;
  const int g    = tid >> 6;          // gate 0..3
  const int mt   = blockIdx.x >> 5;   // batch tile 0..3 (64 rows)
  const int ks   = blockIdx.x & 31;   // unit slice 0..31 (16 units)
  const int m    = lane & 15;
  const int q    = lane >> 4;

  floatx4 acc[4] = {{0,0,0,0},{0,0,0,0},{0,0,0,0},{0,0,0,0}};
  {
    const short* wp = W1 + (long)(g*512 + ks*16 + m)*512 + q*8;
    const short* ap = A1 + (long)(mt*64 + m)*512 + q*8;
    #pragma unroll
    for (int kb = 0; kb < 16; ++kb) {
      short8 b8 = *(const short8*)(wp + kb*32);
      #pragma unroll
      for (int s2 = 0; s2 < 4; ++s2) {
        short8 a8 = *(const short8*)(ap + s2*16*512 + kb*32);
        acc[s2] = __builtin_amdgcn_mfma_f32_16x16x32_bf16(a8, b8, acc[s2], 0, 0, 0);
      }
    }
  }
  if (nseg == 2) {
    const short* wp = W2 + (long)(g*512 + ks*16 + m)*512 + q*8;
    const short* ap = A2 + (long)(mt*64 + m)*512 + q*8;
    #pragma unroll
    for (int kb = 0; kb < 16; ++kb) {
      short8 b8 = *(const short8*)(wp + kb*32);
      #pragma unroll
      for (int s2 = 0; s2 < 4; ++s2) {
        short8 a8 = *(const short8*)(ap + s2*16*512 + kb*32);
        acc[s2] = __builtin_amdgcn_mfma_f32_16x16x32_bf16(a8, b8, acc[s2], 0, 0, 0);
      }
    }
  }

  __shared__ float lds[4][64][17];    // gate x batch-in-block x unit
  #pragma unroll
  for (int s2 = 0; s2 < 4; ++s2)
    #pragma unroll
    for (int r = 0; r < 4; ++r)
      lds[g][s2*16 + q*4 + r][m] = acc[s2][r];
  __syncthreads();

  // epilogue: 64 batches x 16 units = 1024 cells / 256 thr = 4 each
  for (int it = tid; it < 1024; it += 256) {
    const int bl = it >> 4;
    const int uu = it & 15;
    const int bg = mt*64 + bl;
    const int kg = ks*16 + uu;
    float sv = 0.f;
    if (in_mode == 0)      sv = ldf(x, (long)bg*TT + t, dt);
    else if (in_mode == 2) sv = hdr->obuf[bg];
    float gv[4];
    #pragma unroll
    for (int g2 = 0; g2 < 4; ++g2) {
      const int j = g2*512 + kg;
      float v = lds[g2][bl][uu] + bsum[j];
      if (in_mode != 1) v += sv * ldf(wih_col, j, dt);
      gv[g2] = v;
    }
    const float ig = 1.f / (1.f + expf(-gv[0]));
    const float fg = 1.f / (1.f + expf(-gv[1]));
    const float gg = tanhf(gv[2]);
    const float og = 1.f / (1.f + expf(-gv[3]));
    const float cn = fg * C[bg*512 + kg] + ig * gg;
    C[bg*512 + kg]    = cn;
    Hout[bg*512 + kg] = f2bf(og * tanhf(cn));
  }
  if (blockIdx.x == 0 && tid == 0) atomicAdd(&hdr->count, 1);
}

// o[b] = h[b,:].w + bias -> fp32 obuf + fp32 d_out col s. Hin is bf16.
__global__ __launch_bounds__(64) void head_kernel(
    const short* __restrict__ Hin, const void* __restrict__ w,
    const void* __restrict__ bias, float* __restrict__ dout, int s,
    Hdr* __restrict__ hdr)
{
  const int dt = hdr->dtflag;
  const int b = blockIdx.x;
  const int lane = threadIdx.x;
  short8 hv = *(const short8*)(Hin + (long)b*512 + lane*8);
  float sum = 0.f;
  #pragma unroll
  for (int j = 0; j < 8; ++j) sum += bf2f(hv[j]) * ldf(w, lane*8 + j, dt);
  #pragma unroll
  for (int off = 32; off > 0; off >>= 1) sum += __shfl_down(sum, off);
  if (lane == 0) {
    float o = sum + ldf(bias, 0, dt);
    hdr->obuf[b] = o;
    dout[(long)b*FUT + s] = o;          // [B, future] fp32
    if (b == 0) atomicAdd(&hdr->count, 1);
  }
}

__global__ __launch_bounds__(64) void verdict_kernel(
    Hdr* __restrict__ hdr, float* __restrict__ dout)
{
  if (threadIdx.x == 0) {
    int code = -1, m = 0;
    const int cnt = hdr->count;
    const float o0 = hdr->obuf[0];
    if (cnt != 1214)      { code = 3; m = (cnt >> 4) & 127; }
    else if (!(o0 == o0)) { code = 4; m = 0; }
    if (code >= 0) dout[0] = ldexpf(1.f + (float)m / 128.f, 20 + code);
  }
}

extern "C" void kernel_launch(void* const* d_in, const int* in_sizes, int n_in,
                              void* d_out, int out_size, void* d_ws, size_t ws_size,
                              hipStream_t stream) {
  float* dout = (float*)d_out;

  static const int exp_sizes[22] = {
    131072, 1, 2048, 1048576, 2048, 2048, 1048576, 1048576, 2048, 2048,
    512, 1, 2048, 1048576, 2048, 2048, 1048576, 1048576, 2048, 2048, 512, 1};
  int code = -1, m = 0;
  if (n_in != 22) { code = 0; m = n_in & 127; }
  else {
    for (int i = 0; i < 22; ++i)
      if (in_sizes[i] != exp_sizes[i]) { code = 1; m = i; break; }
  }
  if (code < 0 && out_size != BB * FUT) { code = 6; m = (out_size >> 8) & 127; }
  if (code < 0 && (d_ws == nullptr || ws_size < NEED_WS)) {
    code = 2; m = (int)(ws_size >> 20); if (m > 127) m = 127;
  }
  if (code >= 0) {
    float v = ldexpf(1.f + (float)m / 128.f, 20 + code);
    beacon_kernel<<<dim3(1), dim3(64), 0, stream>>>(dout, v);
    return;
  }

  const void* x      = d_in[0];
  const void* w_ih0  = d_in[2];
  const void* w_hh0  = d_in[3];
  const void* b_ih0  = d_in[4];
  const void* b_hh0  = d_in[5];
  const void* w_ih1  = d_in[6];
  const void* w_hh1  = d_in[7];
  const void* b_ih1  = d_in[8];
  const void* b_hh1  = d_in[9];
  const void* fc_w   = d_in[10];
  const void* fc_b   = d_in[11];
  const void* pw_ih0 = d_in[12];
  const void* pw_hh0 = d_in[13];
  const void* pb_ih0 = d_in[14];
  const void* pb_hh0 = d_in[15];
  const void* pw_ih1 = d_in[16];
  const void* pw_hh1 = d_in[17];
  const void* pb_ih1 = d_in[18];
  const void* pb_hh1 = d_in[19];
  const void* pfc_w  = d_in[20];
  const void* pfc_b  = d_in[21];

  char* ws = (char*)d_ws;
  Hdr*   hdr   = (Hdr*)ws;
  float* bs0   = (float*)(ws + OFF_BS0);
  float* bs1   = (float*)(ws + OFF_BS1);
  float* pbs0  = (float*)(ws + OFF_PBS0);
  float* pbs1  = (float*)(ws + OFF_PBS1);
  float* C0    = (float*)(ws + OFF_C0);
  float* C1    = (float*)(ws + OFF_C1);
  short* H0[2] = {(short*)(ws + OFF_H0A), (short*)(ws + OFF_H0B)};
  short* H1[2] = {(short*)(ws + OFF_H1A), (short*)(ws + OFF_H1B)};
  short* wbhh0  = (short*)(ws + OFF_W);
  short* wbih1  = (short*)(ws + OFF_W + 1*WSZ);
  short* wbhh1  = (short*)(ws + OFF_W + 2*WSZ);
  short* pwbhh0 = (short*)(ws + OFF_W + 3*WSZ);
  short* pwbih1 = (short*)(ws + OFF_W + 4*WSZ);
  short* pwbhh1 = (short*)(ws + OFF_W + 5*WSZ);

  hipMemsetAsync(hdr, 0, 8192, stream);
  hipMemsetAsync(C0, 0, 524288, stream);
  hipMemsetAsync(C1, 0, 524288, stream);
  hipMemsetAsync(H0[0], 0, 262144, stream);
  hipMemsetAsync(H1[0], 0, 262144, stream);
  probe1_kernel<<<dim3(1), dim3(256), 0, stream>>>(w_hh0, hdr);

  // one-time weight conversion + bias sums (graph-replayed; ~20 us)
  dim3 cg(1024), cb(256);
  cvt_kernel<<<cg, cb, 0, stream>>>(w_hh0,  wbhh0,  hdr);
  cvt_kernel<<<cg, cb, 0, stream>>>(w_ih1,  wbih1,  hdr);
  cvt_kernel<<<cg, cb, 0, stream>>>(w_hh1,  wbhh1,  hdr);
  cvt_kernel<<<cg, cb, 0, stream>>>(pw_hh0, pwbhh0, hdr);
  cvt_kernel<<<cg, cb, 0, stream>>>(pw_ih1, pwbih1, hdr);
  cvt_kernel<<<cg, cb, 0, stream>>>(pw_hh1, pwbhh1, hdr);
  bias_kernel<<<dim3(8), cb, 0, stream>>>(b_ih0, b_hh0, bs0, hdr);
  bias_kernel<<<dim3(8), cb, 0, stream>>>(b_ih1, b_hh1, bs1, hdr);
  bias_kernel<<<dim3(8), cb, 0, stream>>>(pb_ih0, pb_hh0, pbs0, hdr);
  bias_kernel<<<dim3(8), cb, 0, stream>>>(pb_ih1, pb_hh1, pbs1, hdr);

  dim3 grid(128), blk(256);
  for (int t = 0; t < TT; ++t) {
    const int cur = t & 1, nxt = cur ^ 1;
    lstm_step_mfma<<<grid, blk, 0, stream>>>(H0[cur], nullptr, 1, wbhh0, nullptr,
        bs0, 0, x, t, w_ih0, C0, H0[nxt], hdr);
    lstm_step_mfma<<<grid, blk, 0, stream>>>(H0[nxt], H1[cur], 2, wbih1, wbhh1,
        bs1, 1, nullptr, 0, nullptr, C1, H1[nxt], hdr);
  }
  head_kernel<<<dim3(BB), dim3(64), 0, stream>>>(H1[0], fc_w, fc_b, dout, 0, hdr);

  for (int s = 1; s < FUT; ++s) {
    const int cur = (s - 1) & 1, nxt = cur ^ 1;
    lstm_step_mfma<<<grid, blk, 0, stream>>>(H0[cur], nullptr, 1, pwbhh0, nullptr,
        pbs0, 2, nullptr, 0, pw_ih0, C0, H0[nxt], hdr);
    lstm_step_mfma<<<grid, blk, 0, stream>>>(H0[nxt], H1[cur], 2, pwbih1, pwbhh1,
        pbs1, 1, nullptr, 0, nullptr, C1, H1[nxt], hdr);
    head_kernel<<<dim3(BB), dim3(64), 0, stream>>>(H1[nxt], pfc_w, pfc_b, dout, s, hdr);
  }
  verdict_kernel<<<dim3(1), dim3(64), 0, stream>>>(hdr, dout);
}